// Round 3
// baseline (8284.473 us; speedup 1.0000x reference)
//
#include <hip/hip_runtime.h>

// ---------------------------------------------------------------------------
// GIN 2-layer: out = gin_conv2( relu(gin_conv1(x)) )
//   gin_conv(x,W1,b1,W2,b2) = relu((x + segsum(x[src],dst)) @ W1 + b1) @ W2 + b2
// N=100000 nodes, E=1.6M edges, C: 128 -> 256 -> 256 -> 128
// R3: fix R2's in-place GEMM race. In-place is safe ONLY when one block owns
// the full K-read AND full N-write of its rows (gy=1). N=256 in-place GEMMs
// now use BN=256 single y-block (acc[4][8]/wave). ws stays ~102.9MB (proven).
//   GEMM1: x(f32)+agg -> d_out bf16          BN=128 gy=2 (no alias)
//   GEMM2: d_out -> d_out (in-place)         BN=256 gy=1
//   GEMM3: d_out+agg -> d_out (in-place)     BN=256 gy=1
//   GEMM4: d_out bf16 -> d_out f32 (in-place, equal row extents) BN=128 gy=1
// ---------------------------------------------------------------------------

#define N_NODES 100000
#define N_EDGES 1600000

typedef unsigned short ushort_t;
typedef short bf16x8 __attribute__((ext_vector_type(8)));
typedef float floatx4 __attribute__((ext_vector_type(4)));

static __device__ __forceinline__ ushort_t f2bf(float f) {
    unsigned u = __float_as_uint(f);
    u = (u + 0x7FFFu + ((u >> 16) & 1u)) >> 16;
    return (ushort_t)u;
}
static __device__ __forceinline__ float bf2f(ushort_t u) {
    return __uint_as_float(((unsigned)u) << 16);
}

// ---- convert + transpose weights: W[K][N] fp32 -> Wt[N][K] bf16 ----
__global__ void cvt_w_kernel(const float* __restrict__ W, ushort_t* __restrict__ Wt,
                             int K, int N) {
    int i = blockIdx.x * blockDim.x + threadIdx.x;
    if (i < K * N) {
        int k = i / N;
        int n = i - k * N;
        Wt[(size_t)n * K + k] = f2bf(W[i]);
    }
}

// ---- per-edge scatter: T[dst] += X[src]; X is f32 or bf16, T is f32 ----
template <int C, typename XT>
__global__ __launch_bounds__(256) void edge_agg_kernel(
    const XT* __restrict__ X, float* __restrict__ T,
    const int* __restrict__ src, const int* __restrict__ dst, int nE) {
    constexpr int TPE = C / 4;        // threads per edge, 4 cols each
    constexpr int EPB = 256 / TPE;    // edges per block
    int t = threadIdx.x;
    int e = blockIdx.x * EPB + t / TPE;
    int j = t % TPE;
    if (e >= nE) return;
    int s = src[e];
    int d = dst[e];
    if ((unsigned)s >= (unsigned)N_NODES || (unsigned)d >= (unsigned)N_NODES) return;
    float4 v;
    if constexpr (sizeof(XT) == 4) {
        v = *((const float4*)(X + (size_t)s * C) + j);
    } else {
        ushort4 u = *((const ushort4*)(X + (size_t)s * C) + j);
        v.x = bf2f(u.x); v.y = bf2f(u.y); v.z = bf2f(u.z); v.w = bf2f(u.w);
    }
    float* td = T + (size_t)d * C + j * 4;
    unsafeAtomicAdd(td + 0, v.x);
    unsafeAtomicAdd(td + 1, v.y);
    unsafeAtomicAdd(td + 2, v.z);
    unsafeAtomicAdd(td + 3, v.w);
}

// ---- bf16 MFMA GEMM: C[M][N] = act((A0 [+ A1]) @ W + bias), Wt[N][K] bf16.
// BN = 128 (gy = N/128, 2x2 waves over 128x128) or 256 (gy = 1, 2x2 waves over
// 128x256; in-place safe: one block owns full K-read + full N-write of its rows).
// A and C deliberately NOT __restrict__ (they may alias for in-place calls).
template <int BN, typename AT, bool HAS_ADD, bool RELU, typename OT>
__global__ __launch_bounds__(256) void gemm_kernel(
    const AT* A, const float* __restrict__ Aadd,
    const ushort_t* __restrict__ Wt, const float* __restrict__ bias,
    OT* C, int M, int N, int K) {
    constexpr int BM = 128, BK = 32;
    constexpr int LDW = BK + 8;   // 16B-aligned frag reads, 2-way banks (free)
    constexpr int NI = BN / 32;   // n-tiles per wave (wave covers 64 x BN/2)
    __shared__ ushort_t As[BM * LDW];
    __shared__ ushort_t Bs[BN * LDW];

    const int tid = threadIdx.x;
    const int lane = tid & 63;
    const int wid = tid >> 6;
    const int wm = wid & 1;
    const int wn = wid >> 1;
    const int l15 = lane & 15;
    const int q = lane >> 4;

    const int bm = blockIdx.x * BM;
    const int bn = blockIdx.y * BN;

    floatx4 acc[4][NI];
#pragma unroll
    for (int mi = 0; mi < 4; ++mi)
#pragma unroll
        for (int ni = 0; ni < NI; ++ni) {
            floatx4 z = {0.f, 0.f, 0.f, 0.f};
            acc[mi][ni] = z;
        }

    for (int kt = 0; kt < K; kt += BK) {
        // stage A tile (BM x BK) -> bf16 LDS
#pragma unroll
        for (int p = 0; p < 4; ++p) {
            int i = p * 256 + tid;
            int row = i >> 3;
            int c4 = i & 7;
            int gr = bm + row;
            if (gr > M - 1) gr = M - 1;  // clamp stays inside this block's rows
            size_t off = (size_t)gr * K + kt + c4 * 4;
            ushort4 u;
            if constexpr (sizeof(AT) == 4) {
                float4 v = *(const float4*)(A + off);
                if constexpr (HAS_ADD) {
                    float4 w = *(const float4*)(Aadd + off);
                    v.x += w.x; v.y += w.y; v.z += w.z; v.w += w.w;
                }
                u.x = f2bf(v.x); u.y = f2bf(v.y); u.z = f2bf(v.z); u.w = f2bf(v.w);
            } else {
                ushort4 a = *(const ushort4*)(A + off);
                if constexpr (HAS_ADD) {
                    float4 w = *(const float4*)(Aadd + off);
                    u.x = f2bf(bf2f(a.x) + w.x);
                    u.y = f2bf(bf2f(a.y) + w.y);
                    u.z = f2bf(bf2f(a.z) + w.z);
                    u.w = f2bf(bf2f(a.w) + w.w);
                } else {
                    u = a;
                }
            }
            *(ushort4*)&As[row * LDW + c4 * 4] = u;
        }
        // stage B tile (BN x BK) from pre-transposed bf16 weights
#pragma unroll
        for (int p = 0; p < NI; ++p) {
            int i = p * 256 + tid;
            int row = i >> 3;
            int c4 = i & 7;
            ushort4 u = *(const ushort4*)(Wt + (size_t)(bn + row) * K + kt + c4 * 4);
            *(ushort4*)&Bs[row * LDW + c4 * 4] = u;
        }
        __syncthreads();

        bf16x8 av[4], bv[NI];
#pragma unroll
        for (int mi = 0; mi < 4; ++mi)
            av[mi] = *(const bf16x8*)&As[(wm * 64 + mi * 16 + l15) * LDW + q * 8];
#pragma unroll
        for (int ni = 0; ni < NI; ++ni)
            bv[ni] = *(const bf16x8*)&Bs[(wn * (BN / 2) + ni * 16 + l15) * LDW + q * 8];
#pragma unroll
        for (int mi = 0; mi < 4; ++mi)
#pragma unroll
            for (int ni = 0; ni < NI; ++ni)
                acc[mi][ni] = __builtin_amdgcn_mfma_f32_16x16x32_bf16(
                    av[mi], bv[ni], acc[mi][ni], 0, 0, 0);
        __syncthreads();
    }

    // epilogue: C/D frag layout col = lane&15, row = quad*4 + reg
    float bval[NI];
#pragma unroll
    for (int ni = 0; ni < NI; ++ni)
        bval[ni] = bias[bn + wn * (BN / 2) + ni * 16 + l15];
#pragma unroll
    for (int mi = 0; mi < 4; ++mi) {
#pragma unroll
        for (int r = 0; r < 4; ++r) {
            int row = bm + wm * 64 + mi * 16 + q * 4 + r;
            if (row < M) {
#pragma unroll
                for (int ni = 0; ni < NI; ++ni) {
                    int col = bn + wn * (BN / 2) + ni * 16 + l15;
                    float v = acc[mi][ni][r] + bval[ni];
                    if (RELU) v = v > 0.f ? v : 0.f;
                    if constexpr (sizeof(OT) == 2)
                        C[(size_t)row * N + col] = f2bf(v);
                    else
                        C[(size_t)row * N + col] = v;
                }
            }
        }
    }
}

extern "C" void kernel_launch(void* const* d_in, const int* in_sizes, int n_in,
                              void* d_out, int out_size, void* d_ws, size_t ws_size,
                              hipStream_t stream) {
    const float* x   = (const float*)d_in[0];
    const int*   ei  = (const int*)d_in[1];
    const float* W1a = (const float*)d_in[2];
    const float* b1a = (const float*)d_in[3];
    const float* W2a = (const float*)d_in[4];
    const float* b2a = (const float*)d_in[5];
    const float* W1b = (const float*)d_in[6];
    const float* b1b = (const float*)d_in[7];
    const float* W2b = (const float*)d_in[8];
    const float* b2b = (const float*)d_in[9];
    const int* src = ei;
    const int* dst = ei + N_EDGES;
    float* out = (float*)d_out;

    // workspace: bf16 transposed weights + one f32 agg region (102.4MB)
    char* base = (char*)d_ws;
    size_t o = 0;
    ushort_t* wt1a = (ushort_t*)(base + o); o += 128 * 256 * 2;
    ushort_t* wt2a = (ushort_t*)(base + o); o += 256 * 256 * 2;
    ushort_t* wt1b = (ushort_t*)(base + o); o += 256 * 256 * 2;
    ushort_t* wt2b = (ushort_t*)(base + o); o += 256 * 128 * 2;
    o = (o + 255) & ~(size_t)255;
    float* agg = (float*)(base + o);
    o += (size_t)N_NODES * 256 * 4;          // total ~102.8MB (proven to fit)
    (void)ws_size; (void)o; (void)in_sizes; (void)n_in; (void)out_size;

    // intermediates u1/h/u2: bf16 N*256 = 51.2MB, aliased onto d_out
    ushort_t* inter = (ushort_t*)d_out;

    cvt_w_kernel<<<(128 * 256 + 255) / 256, 256, 0, stream>>>(W1a, wt1a, 128, 256);
    cvt_w_kernel<<<(256 * 256 + 255) / 256, 256, 0, stream>>>(W2a, wt2a, 256, 256);
    cvt_w_kernel<<<(256 * 256 + 255) / 256, 256, 0, stream>>>(W1b, wt1b, 256, 256);
    cvt_w_kernel<<<(256 * 128 + 255) / 256, 256, 0, stream>>>(W2b, wt2b, 256, 128);

    const int gm = (N_NODES + 127) / 128;  // 782

    // ---- layer 1 ----
    hipMemsetAsync(agg, 0, (size_t)N_NODES * 128 * 4, stream);
    edge_agg_kernel<128, float><<<N_EDGES / 8, 256, 0, stream>>>(
        x, agg, src, dst, N_EDGES);
    // u1 = relu((x+agg) @ W1a + b1a)        (writes d_out, reads x/agg)
    gemm_kernel<128, float, true, true, ushort_t><<<dim3(gm, 2), 256, 0, stream>>>(
        x, agg, wt1a, b1a, inter, N_NODES, 256, 128);
    // h = relu(u1 @ W2a + b2a)              (in-place, BN=256, gy=1)
    gemm_kernel<256, ushort_t, false, true, ushort_t><<<dim3(gm, 1), 256, 0, stream>>>(
        inter, nullptr, wt2a, b2a, inter, N_NODES, 256, 256);

    // ---- layer 2 ----
    hipMemsetAsync(agg, 0, (size_t)N_NODES * 256 * 4, stream);
    edge_agg_kernel<256, ushort_t><<<N_EDGES / 4, 256, 0, stream>>>(
        inter, agg, src, dst, N_EDGES);
    // u2 = relu((h+agg) @ W1b + b1b)        (in-place, BN=256, gy=1)
    gemm_kernel<256, ushort_t, true, true, ushort_t><<<dim3(gm, 1), 256, 0, stream>>>(
        inter, agg, wt1b, b1b, inter, N_NODES, 256, 256);
    // out = u2 @ W2b + b2b                  (in-place, equal row extents, f32 out)
    gemm_kernel<128, ushort_t, false, false, float><<<dim3(gm, 1), 256, 0, stream>>>(
        inter, nullptr, wt2b, b2b, out, N_NODES, 128, 256);
}

// Round 4
// 676.345 us; speedup vs baseline: 12.2489x; 12.2489x over previous
//
#include <hip/hip_runtime.h>

// ---------------------------------------------------------------------------
// GIN 2-layer: out = gin_conv2( relu(gin_conv1(x)) )
// N=100000 nodes, E=1.6M edges, C: 128 -> 256 -> 256 -> 128
// R4: replace fp32 atomic scatter aggregation (R3: 7.9ms, WRITE_SIZE 6.5GB of
// L2 thrash) with per-launch CSR build + per-node gather-sum:
//   hist -> 3-kernel scan -> fill  (int atomics only, ~2x1.6M)
//   agg_gather: 1 wave/node, lane owns 8B of row, shfl-broadcast neighbor
//   indices, 4-way unrolled gather, fp32 accum, writes t = x + sum as bf16.
// GEMMs (bf16 MFMA 16x16x32, BM=128 BK=32) unchanged; all A inputs now bf16.
// In-place rule: alias of A and C in d_out requires gy=1 (block owns full
// K-read + full N-write of its rows).
// ---------------------------------------------------------------------------

#define N_NODES 100000
#define N_EDGES 1600000

typedef unsigned short ushort_t;
typedef short bf16x8 __attribute__((ext_vector_type(8)));
typedef float floatx4 __attribute__((ext_vector_type(4)));

static __device__ __forceinline__ ushort_t f2bf(float f) {
    unsigned u = __float_as_uint(f);
    u = (u + 0x7FFFu + ((u >> 16) & 1u)) >> 16;
    return (ushort_t)u;
}
static __device__ __forceinline__ float bf2f(ushort_t u) {
    return __uint_as_float(((unsigned)u) << 16);
}

// ---- convert + transpose weights: W[K][N] fp32 -> Wt[N][K] bf16 ----
__global__ void cvt_w_kernel(const float* __restrict__ W, ushort_t* __restrict__ Wt,
                             int K, int N) {
    int i = blockIdx.x * blockDim.x + threadIdx.x;
    if (i < K * N) {
        int k = i / N;
        int n = i - k * N;
        Wt[(size_t)n * K + k] = f2bf(W[i]);
    }
}

// ---- CSR build ----
__global__ __launch_bounds__(256) void hist_kernel(const int* __restrict__ dst,
                                                   int* __restrict__ deg, int nE) {
    int e = blockIdx.x * blockDim.x + threadIdx.x;
    if (e < nE) {
        int d = dst[e];
        if ((unsigned)d < (unsigned)N_NODES) atomicAdd(&deg[d], 1);
    }
}

// block sums of 1024-element chunks
__global__ __launch_bounds__(256) void scan1_kernel(const int* __restrict__ deg,
                                                    int* __restrict__ bsum, int n) {
    __shared__ int l[256];
    int b = blockIdx.x, t = threadIdx.x;
    int base = b * 1024 + t * 4;
    int s = 0;
#pragma unroll
    for (int k = 0; k < 4; ++k) {
        int i = base + k;
        if (i < n) s += deg[i];
    }
    l[t] = s;
    __syncthreads();
    for (int off = 128; off > 0; off >>= 1) {
        if (t < off) l[t] += l[t + off];
        __syncthreads();
    }
    if (t == 0) bsum[b] = l[0];
}

// exclusive scan of <=128 block sums (single block)
__global__ __launch_bounds__(128) void scan2_kernel(const int* __restrict__ bsum,
                                                    int* __restrict__ boff, int nb) {
    __shared__ int l[128];
    int t = threadIdx.x;
    int v = (t < nb) ? bsum[t] : 0;
    l[t] = v;
    __syncthreads();
    for (int off = 1; off < 128; off <<= 1) {
        int add = (t >= off) ? l[t - off] : 0;
        __syncthreads();
        l[t] += add;
        __syncthreads();
    }
    if (t < nb) boff[t] = l[t] - v;  // exclusive
}

// final exclusive scan -> row_ptr (and cursor copy)
__global__ __launch_bounds__(256) void scan3_kernel(const int* __restrict__ deg,
                                                    const int* __restrict__ boff,
                                                    int* __restrict__ row_ptr,
                                                    int* __restrict__ cursor, int n) {
    __shared__ int l[256];
    int b = blockIdx.x, t = threadIdx.x;
    int base = b * 1024 + t * 4;
    int d[4];
    int s = 0;
#pragma unroll
    for (int k = 0; k < 4; ++k) {
        int i = base + k;
        d[k] = (i < n) ? deg[i] : 0;
        s += d[k];
    }
    l[t] = s;
    __syncthreads();
    for (int off = 1; off < 256; off <<= 1) {
        int add = (t >= off) ? l[t - off] : 0;
        __syncthreads();
        l[t] += add;
        __syncthreads();
    }
    int run = boff[b] + l[t] - s;  // exclusive prefix at this thread's chunk
#pragma unroll
    for (int k = 0; k < 4; ++k) {
        int i = base + k;
        if (i < n) {
            row_ptr[i] = run;
            cursor[i] = run;
        }
        run += d[k];
    }
}

__global__ __launch_bounds__(256) void fill_kernel(const int* __restrict__ src,
                                                   const int* __restrict__ dst,
                                                   int* __restrict__ cursor,
                                                   int* __restrict__ csr_src, int nE) {
    int e = blockIdx.x * blockDim.x + threadIdx.x;
    if (e < nE) {
        int s = src[e];
        int d = dst[e];
        if ((unsigned)s >= (unsigned)N_NODES || (unsigned)d >= (unsigned)N_NODES) return;
        int pos = atomicAdd(&cursor[d], 1);
        csr_src[pos] = s;
    }
}

// ---- per-node gather aggregation: T[i] = X[i] + sum_{j in N(i)} X[j], bf16 out
// One wave per node; lane owns 8 bytes (VF elems) of the C-wide row.
template <int C, typename XT>
__global__ __launch_bounds__(256) void agg_gather_kernel(
    const XT* __restrict__ X, ushort_t* __restrict__ T,
    const int* __restrict__ row_ptr, const int* __restrict__ deg,
    const int* __restrict__ csr_src, int nN) {
    constexpr int VF = 8 / sizeof(XT);  // 2 f32 or 4 bf16 per lane
    static_assert(64 * VF == C, "lane coverage must equal row width");
    const int lane = threadIdx.x & 63;
    const int wid = threadIdx.x >> 6;
    const int node = blockIdx.x * 4 + wid;
    if (node >= nN) return;

    float acc[VF];
    {
        const XT* row = X + (size_t)node * C + lane * VF;
        if constexpr (sizeof(XT) == 4) {
            float2 v = *(const float2*)row;
            acc[0] = v.x; acc[1] = v.y;
        } else {
            ushort4 u = *(const ushort4*)row;
            acc[0] = bf2f(u.x); acc[1] = bf2f(u.y);
            acc[2] = bf2f(u.z); acc[3] = bf2f(u.w);
        }
    }

    const int base = row_ptr[node];
    const int dg = deg[node];
    for (int j0 = 0; j0 < dg; j0 += 64) {
        int cnt = dg - j0;
        if (cnt > 64) cnt = 64;
        int nidx = (lane < cnt) ? csr_src[base + j0 + lane] : 0;
        int j = 0;
        for (; j + 3 < cnt; j += 4) {  // 4 outstanding gathers
            int s0 = __shfl(nidx, j);
            int s1 = __shfl(nidx, j + 1);
            int s2 = __shfl(nidx, j + 2);
            int s3 = __shfl(nidx, j + 3);
            if constexpr (sizeof(XT) == 4) {
                float2 v0 = *(const float2*)(X + (size_t)s0 * C + lane * VF);
                float2 v1 = *(const float2*)(X + (size_t)s1 * C + lane * VF);
                float2 v2 = *(const float2*)(X + (size_t)s2 * C + lane * VF);
                float2 v3 = *(const float2*)(X + (size_t)s3 * C + lane * VF);
                acc[0] += v0.x + v1.x + v2.x + v3.x;
                acc[1] += v0.y + v1.y + v2.y + v3.y;
            } else {
                ushort4 u0 = *(const ushort4*)(X + (size_t)s0 * C + lane * VF);
                ushort4 u1 = *(const ushort4*)(X + (size_t)s1 * C + lane * VF);
                ushort4 u2 = *(const ushort4*)(X + (size_t)s2 * C + lane * VF);
                ushort4 u3 = *(const ushort4*)(X + (size_t)s3 * C + lane * VF);
                acc[0] += bf2f(u0.x) + bf2f(u1.x) + bf2f(u2.x) + bf2f(u3.x);
                acc[1] += bf2f(u0.y) + bf2f(u1.y) + bf2f(u2.y) + bf2f(u3.y);
                acc[2] += bf2f(u0.z) + bf2f(u1.z) + bf2f(u2.z) + bf2f(u3.z);
                acc[3] += bf2f(u0.w) + bf2f(u1.w) + bf2f(u2.w) + bf2f(u3.w);
            }
        }
        for (; j < cnt; ++j) {
            int s0 = __shfl(nidx, j);
            if constexpr (sizeof(XT) == 4) {
                float2 v0 = *(const float2*)(X + (size_t)s0 * C + lane * VF);
                acc[0] += v0.x; acc[1] += v0.y;
            } else {
                ushort4 u0 = *(const ushort4*)(X + (size_t)s0 * C + lane * VF);
                acc[0] += bf2f(u0.x); acc[1] += bf2f(u0.y);
                acc[2] += bf2f(u0.z); acc[3] += bf2f(u0.w);
            }
        }
    }

    ushort_t* o = T + (size_t)node * C + lane * VF;
    if constexpr (VF == 2) {
        ushort2 w;
        w.x = f2bf(acc[0]); w.y = f2bf(acc[1]);
        *(ushort2*)o = w;
    } else {
        ushort4 w;
        w.x = f2bf(acc[0]); w.y = f2bf(acc[1]);
        w.z = f2bf(acc[2]); w.w = f2bf(acc[3]);
        *(ushort4*)o = w;
    }
}

// ---- bf16 MFMA GEMM: C[M][N] = act(A @ W + bias), Wt[N][K] bf16, A bf16.
// BN=128 (gy=N/128) or BN=256 (gy=1, required for in-place d_out calls).
template <int BN, bool RELU, typename OT>
__global__ __launch_bounds__(256) void gemm_kernel(
    const ushort_t* A, const ushort_t* __restrict__ Wt,
    const float* __restrict__ bias, OT* C, int M, int N, int K) {
    constexpr int BM = 128, BK = 32;
    constexpr int LDW = BK + 8;   // 16B-aligned frag reads, 2-way banks (free)
    constexpr int NI = BN / 32;   // n-tiles per wave
    __shared__ ushort_t As[BM * LDW];
    __shared__ ushort_t Bs[BN * LDW];

    const int tid = threadIdx.x;
    const int lane = tid & 63;
    const int wid = tid >> 6;
    const int wm = wid & 1;
    const int wn = wid >> 1;
    const int l15 = lane & 15;
    const int q = lane >> 4;

    const int bm = blockIdx.x * BM;
    const int bn = blockIdx.y * BN;

    floatx4 acc[4][NI];
#pragma unroll
    for (int mi = 0; mi < 4; ++mi)
#pragma unroll
        for (int ni = 0; ni < NI; ++ni) {
            floatx4 z = {0.f, 0.f, 0.f, 0.f};
            acc[mi][ni] = z;
        }

    for (int kt = 0; kt < K; kt += BK) {
#pragma unroll
        for (int p = 0; p < 4; ++p) {
            int i = p * 256 + tid;
            int row = i >> 3;
            int c4 = i & 7;
            int gr = bm + row;
            if (gr > M - 1) gr = M - 1;  // clamp stays inside this block's rows
            ushort4 u = *(const ushort4*)(A + (size_t)gr * K + kt + c4 * 4);
            *(ushort4*)&As[row * LDW + c4 * 4] = u;
        }
#pragma unroll
        for (int p = 0; p < NI; ++p) {
            int i = p * 256 + tid;
            int row = i >> 3;
            int c4 = i & 7;
            ushort4 u = *(const ushort4*)(Wt + (size_t)(bn + row) * K + kt + c4 * 4);
            *(ushort4*)&Bs[row * LDW + c4 * 4] = u;
        }
        __syncthreads();

        bf16x8 av[4], bv[NI];
#pragma unroll
        for (int mi = 0; mi < 4; ++mi)
            av[mi] = *(const bf16x8*)&As[(wm * 64 + mi * 16 + l15) * LDW + q * 8];
#pragma unroll
        for (int ni = 0; ni < NI; ++ni)
            bv[ni] = *(const bf16x8*)&Bs[(wn * (BN / 2) + ni * 16 + l15) * LDW + q * 8];
#pragma unroll
        for (int mi = 0; mi < 4; ++mi)
#pragma unroll
            for (int ni = 0; ni < NI; ++ni)
                acc[mi][ni] = __builtin_amdgcn_mfma_f32_16x16x32_bf16(
                    av[mi], bv[ni], acc[mi][ni], 0, 0, 0);
        __syncthreads();
    }

    float bval[NI];
#pragma unroll
    for (int ni = 0; ni < NI; ++ni)
        bval[ni] = bias[bn + wn * (BN / 2) + ni * 16 + l15];
#pragma unroll
    for (int mi = 0; mi < 4; ++mi) {
#pragma unroll
        for (int r = 0; r < 4; ++r) {
            int row = bm + wm * 64 + mi * 16 + q * 4 + r;
            if (row < M) {
#pragma unroll
                for (int ni = 0; ni < NI; ++ni) {
                    int col = bn + wn * (BN / 2) + ni * 16 + l15;
                    float v = acc[mi][ni][r] + bval[ni];
                    if (RELU) v = v > 0.f ? v : 0.f;
                    if constexpr (sizeof(OT) == 2)
                        C[(size_t)row * N + col] = f2bf(v);
                    else
                        C[(size_t)row * N + col] = v;
                }
            }
        }
    }
}

extern "C" void kernel_launch(void* const* d_in, const int* in_sizes, int n_in,
                              void* d_out, int out_size, void* d_ws, size_t ws_size,
                              hipStream_t stream) {
    const float* x   = (const float*)d_in[0];
    const int*   ei  = (const int*)d_in[1];
    const float* W1a = (const float*)d_in[2];
    const float* b1a = (const float*)d_in[3];
    const float* W2a = (const float*)d_in[4];
    const float* b2a = (const float*)d_in[5];
    const float* W1b = (const float*)d_in[6];
    const float* b1b = (const float*)d_in[7];
    const float* W2b = (const float*)d_in[8];
    const float* b2b = (const float*)d_in[9];
    const int* src = ei;
    const int* dst = ei + N_EDGES;
    float* out = (float*)d_out;

    // ---- workspace layout (~85MB; 103MB proven to fit) ----
    char* base = (char*)d_ws;
    size_t o = 0;
    ushort_t* wt1a = (ushort_t*)(base + o); o += 128 * 256 * 2;
    ushort_t* wt2a = (ushort_t*)(base + o); o += 256 * 256 * 2;
    ushort_t* wt1b = (ushort_t*)(base + o); o += 256 * 256 * 2;
    ushort_t* wt2b = (ushort_t*)(base + o); o += 256 * 128 * 2;
    o = (o + 255) & ~(size_t)255;
    int* deg     = (int*)(base + o); o += (size_t)N_NODES * 4;
    int* row_ptr = (int*)(base + o); o += (size_t)N_NODES * 4;
    int* cursor  = (int*)(base + o); o += (size_t)N_NODES * 4;
    int* bsum    = (int*)(base + o); o += 128 * 4;
    int* boff    = (int*)(base + o); o += 128 * 4;
    o = (o + 255) & ~(size_t)255;
    int* csr_src = (int*)(base + o); o += (size_t)N_EDGES * 4;
    o = (o + 255) & ~(size_t)255;
    ushort_t* t1 = (ushort_t*)(base + o); o += (size_t)N_NODES * 128 * 2;
    ushort_t* t2 = (ushort_t*)(base + o); o += (size_t)N_NODES * 256 * 2;
    (void)ws_size; (void)o; (void)in_sizes; (void)n_in; (void)out_size;

    ushort_t* inter = (ushort_t*)d_out;  // u1 / h / u2 live in d_out (bf16 N*256)

    // ---- weights -> bf16 transposed ----
    cvt_w_kernel<<<(128 * 256 + 255) / 256, 256, 0, stream>>>(W1a, wt1a, 128, 256);
    cvt_w_kernel<<<(256 * 256 + 255) / 256, 256, 0, stream>>>(W2a, wt2a, 256, 256);
    cvt_w_kernel<<<(256 * 256 + 255) / 256, 256, 0, stream>>>(W1b, wt1b, 256, 256);
    cvt_w_kernel<<<(256 * 128 + 255) / 256, 256, 0, stream>>>(W2b, wt2b, 256, 128);

    // ---- CSR build (once; reused by both layers) ----
    const int NB = (N_NODES + 1023) / 1024;  // 98
    hipMemsetAsync(deg, 0, (size_t)N_NODES * 4, stream);
    hist_kernel<<<(N_EDGES + 255) / 256, 256, 0, stream>>>(dst, deg, N_EDGES);
    scan1_kernel<<<NB, 256, 0, stream>>>(deg, bsum, N_NODES);
    scan2_kernel<<<1, 128, 0, stream>>>(bsum, boff, NB);
    scan3_kernel<<<NB, 256, 0, stream>>>(deg, boff, row_ptr, cursor, N_NODES);
    fill_kernel<<<(N_EDGES + 255) / 256, 256, 0, stream>>>(src, dst, cursor, csr_src,
                                                           N_EDGES);

    const int gm = (N_NODES + 127) / 128;    // 782
    const int ga = (N_NODES + 3) / 4;        // 25000

    // ---- layer 1 ----
    agg_gather_kernel<128, float><<<ga, 256, 0, stream>>>(x, t1, row_ptr, deg,
                                                          csr_src, N_NODES);
    gemm_kernel<128, true, ushort_t><<<dim3(gm, 2), 256, 0, stream>>>(
        t1, wt1a, b1a, inter, N_NODES, 256, 128);
    gemm_kernel<256, true, ushort_t><<<dim3(gm, 1), 256, 0, stream>>>(
        inter, wt2a, b2a, inter, N_NODES, 256, 256);   // in-place, gy=1

    // ---- layer 2 ----
    agg_gather_kernel<256, ushort_t><<<ga, 256, 0, stream>>>(inter, t2, row_ptr, deg,
                                                             csr_src, N_NODES);
    gemm_kernel<128, true, ushort_t><<<dim3(gm, 2), 256, 0, stream>>>(
        t2, wt1b, b1b, inter, N_NODES, 256, 256);      // ws -> d_out, no alias
    gemm_kernel<128, false, float><<<dim3(gm, 1), 256, 0, stream>>>(
        inter, wt2b, b2b, out, N_NODES, 128, 256);     // in-place, equal row extents
}

// Round 5
// 626.420 us; speedup vs baseline: 13.2251x; 1.0797x over previous
//
#include <hip/hip_runtime.h>

// ---------------------------------------------------------------------------
// GIN 2-layer: out = gin_conv2( relu(gin_conv1(x)) )
// N=100000 nodes, E=1.6M edges, C: 128 -> 256 -> 256 -> 128
// R5 (from R4 @ 676us):
//  - hist/fill bucketed by dst>>13 via blockIdx.y (13 loose passes): confines
//    the scatter's active write region to ~1MB -> L2-resident, kills the
//    105MB WRITE_SIZE line thrash seen in R4's fill (130us top dispatch).
//  - u1 moved to ws (reuses t2 slot; dead before agg2 writes t2): GEMM2 is
//    now out-of-place BN=128/gy=2. Only GEMM4 is in-place (gy=1, equal
//    512B row extents: u2 bf16 256c == out f32 128c).
//  - 4 cvt_w launches fused into one.
// Aggregation: CSR gather, 1 wave/node, lane owns 8B of row, shfl-broadcast
// neighbor indices, 4-wide unroll, fp32 accum, bf16 out (self-term fused).
// GEMM: bf16 MFMA 16x16x32, BM=128 BN=128 BK=32, 2x2 waves, LDS pad +8.
// ---------------------------------------------------------------------------

#define N_NODES 100000
#define N_EDGES 1600000
#define NBUCK 13  // buckets = dst >> 13 -> 0..12

typedef unsigned short ushort_t;
typedef short bf16x8 __attribute__((ext_vector_type(8)));
typedef float floatx4 __attribute__((ext_vector_type(4)));

static __device__ __forceinline__ ushort_t f2bf(float f) {
    unsigned u = __float_as_uint(f);
    u = (u + 0x7FFFu + ((u >> 16) & 1u)) >> 16;
    return (ushort_t)u;
}
static __device__ __forceinline__ float bf2f(ushort_t u) {
    return __uint_as_float(((unsigned)u) << 16);
}

// ---- all four weights -> bf16 transposed, one launch ----
__global__ __launch_bounds__(256) void cvt_all_kernel(
    const float* __restrict__ W1a, const float* __restrict__ W2a,
    const float* __restrict__ W1b, const float* __restrict__ W2b,
    ushort_t* __restrict__ wt1a, ushort_t* __restrict__ wt2a,
    ushort_t* __restrict__ wt1b, ushort_t* __restrict__ wt2b) {
    int i = blockIdx.x * 256 + threadIdx.x;
    if (i < 32768) {                       // W1a [128][256]
        int k = i >> 8, n = i & 255;
        wt1a[n * 128 + k] = f2bf(W1a[i]);
    } else if (i < 98304) {                // W2a [256][256]
        int j = i - 32768, k = j >> 8, n = j & 255;
        wt2a[n * 256 + k] = f2bf(W2a[j]);
    } else if (i < 163840) {               // W1b [256][256]
        int j = i - 98304, k = j >> 8, n = j & 255;
        wt1b[n * 256 + k] = f2bf(W1b[j]);
    } else if (i < 196608) {               // W2b [256][128]
        int j = i - 163840, k = j >> 7, n = j & 127;
        wt2b[n * 256 + k] = f2bf(W2b[j]);
    }
}

// ---- CSR build, bucketed: blockIdx.y owns dst range [y<<13, (y+1)<<13) ----
__global__ __launch_bounds__(256) void hist_kernel(const int* __restrict__ src,
                                                   const int* __restrict__ dst,
                                                   int* __restrict__ deg, int nE) {
    const int bucket = blockIdx.y;
    for (int e = blockIdx.x * 256 + threadIdx.x; e < nE; e += gridDim.x * 256) {
        int d = dst[e];
        int s = src[e];
        if ((unsigned)d < (unsigned)N_NODES && (unsigned)s < (unsigned)N_NODES &&
            (d >> 13) == bucket)
            atomicAdd(&deg[d], 1);
    }
}

__global__ __launch_bounds__(256) void fill_kernel(const int* __restrict__ src,
                                                   const int* __restrict__ dst,
                                                   int* __restrict__ cursor,
                                                   int* __restrict__ csr_src, int nE) {
    const int bucket = blockIdx.y;
    for (int e = blockIdx.x * 256 + threadIdx.x; e < nE; e += gridDim.x * 256) {
        int d = dst[e];
        int s = src[e];
        if ((unsigned)d < (unsigned)N_NODES && (unsigned)s < (unsigned)N_NODES &&
            (d >> 13) == bucket) {
            int pos = atomicAdd(&cursor[d], 1);
            csr_src[pos] = s;
        }
    }
}

// ---- scan: deg -> row_ptr (exclusive), cursor copy ----
__global__ __launch_bounds__(256) void scan1_kernel(const int* __restrict__ deg,
                                                    int* __restrict__ bsum, int n) {
    __shared__ int l[256];
    int b = blockIdx.x, t = threadIdx.x;
    int base = b * 1024 + t * 4;
    int s = 0;
#pragma unroll
    for (int k = 0; k < 4; ++k) {
        int i = base + k;
        if (i < n) s += deg[i];
    }
    l[t] = s;
    __syncthreads();
    for (int off = 128; off > 0; off >>= 1) {
        if (t < off) l[t] += l[t + off];
        __syncthreads();
    }
    if (t == 0) bsum[b] = l[0];
}

__global__ __launch_bounds__(128) void scan2_kernel(const int* __restrict__ bsum,
                                                    int* __restrict__ boff, int nb) {
    __shared__ int l[128];
    int t = threadIdx.x;
    int v = (t < nb) ? bsum[t] : 0;
    l[t] = v;
    __syncthreads();
    for (int off = 1; off < 128; off <<= 1) {
        int add = (t >= off) ? l[t - off] : 0;
        __syncthreads();
        l[t] += add;
        __syncthreads();
    }
    if (t < nb) boff[t] = l[t] - v;  // exclusive
}

__global__ __launch_bounds__(256) void scan3_kernel(const int* __restrict__ deg,
                                                    const int* __restrict__ boff,
                                                    int* __restrict__ row_ptr,
                                                    int* __restrict__ cursor, int n) {
    __shared__ int l[256];
    int b = blockIdx.x, t = threadIdx.x;
    int base = b * 1024 + t * 4;
    int d[4];
    int s = 0;
#pragma unroll
    for (int k = 0; k < 4; ++k) {
        int i = base + k;
        d[k] = (i < n) ? deg[i] : 0;
        s += d[k];
    }
    l[t] = s;
    __syncthreads();
    for (int off = 1; off < 256; off <<= 1) {
        int add = (t >= off) ? l[t - off] : 0;
        __syncthreads();
        l[t] += add;
        __syncthreads();
    }
    int run = boff[b] + l[t] - s;
#pragma unroll
    for (int k = 0; k < 4; ++k) {
        int i = base + k;
        if (i < n) {
            row_ptr[i] = run;
            cursor[i] = run;
        }
        run += d[k];
    }
}

// ---- per-node gather: T[i] = X[i] + sum_{j in N(i)} X[j], bf16 out ----
template <int C, typename XT>
__global__ __launch_bounds__(256) void agg_gather_kernel(
    const XT* __restrict__ X, ushort_t* __restrict__ T,
    const int* __restrict__ row_ptr, const int* __restrict__ deg,
    const int* __restrict__ csr_src, int nN) {
    constexpr int VF = 8 / sizeof(XT);  // 2 f32 or 4 bf16 per lane
    static_assert(64 * VF == C, "lane coverage must equal row width");
    const int lane = threadIdx.x & 63;
    const int wid = threadIdx.x >> 6;
    const int node = blockIdx.x * 4 + wid;
    if (node >= nN) return;

    float acc[VF];
    {
        const XT* row = X + (size_t)node * C + lane * VF;
        if constexpr (sizeof(XT) == 4) {
            float2 v = *(const float2*)row;
            acc[0] = v.x; acc[1] = v.y;
        } else {
            ushort4 u = *(const ushort4*)row;
            acc[0] = bf2f(u.x); acc[1] = bf2f(u.y);
            acc[2] = bf2f(u.z); acc[3] = bf2f(u.w);
        }
    }

    const int base = row_ptr[node];
    const int dg = deg[node];
    for (int j0 = 0; j0 < dg; j0 += 64) {
        int cnt = dg - j0;
        if (cnt > 64) cnt = 64;
        int nidx = (lane < cnt) ? csr_src[base + j0 + lane] : 0;
        if ((unsigned)nidx >= (unsigned)N_NODES) nidx = 0;  // safety clamp
        int j = 0;
        for (; j + 3 < cnt; j += 4) {
            int s0 = __shfl(nidx, j);
            int s1 = __shfl(nidx, j + 1);
            int s2 = __shfl(nidx, j + 2);
            int s3 = __shfl(nidx, j + 3);
            if constexpr (sizeof(XT) == 4) {
                float2 v0 = *(const float2*)(X + (size_t)s0 * C + lane * VF);
                float2 v1 = *(const float2*)(X + (size_t)s1 * C + lane * VF);
                float2 v2 = *(const float2*)(X + (size_t)s2 * C + lane * VF);
                float2 v3 = *(const float2*)(X + (size_t)s3 * C + lane * VF);
                acc[0] += v0.x + v1.x + v2.x + v3.x;
                acc[1] += v0.y + v1.y + v2.y + v3.y;
            } else {
                ushort4 u0 = *(const ushort4*)(X + (size_t)s0 * C + lane * VF);
                ushort4 u1 = *(const ushort4*)(X + (size_t)s1 * C + lane * VF);
                ushort4 u2 = *(const ushort4*)(X + (size_t)s2 * C + lane * VF);
                ushort4 u3 = *(const ushort4*)(X + (size_t)s3 * C + lane * VF);
                acc[0] += bf2f(u0.x) + bf2f(u1.x) + bf2f(u2.x) + bf2f(u3.x);
                acc[1] += bf2f(u0.y) + bf2f(u1.y) + bf2f(u2.y) + bf2f(u3.y);
                acc[2] += bf2f(u0.z) + bf2f(u1.z) + bf2f(u2.z) + bf2f(u3.z);
                acc[3] += bf2f(u0.w) + bf2f(u1.w) + bf2f(u2.w) + bf2f(u3.w);
            }
        }
        for (; j < cnt; ++j) {
            int s0 = __shfl(nidx, j);
            if constexpr (sizeof(XT) == 4) {
                float2 v0 = *(const float2*)(X + (size_t)s0 * C + lane * VF);
                acc[0] += v0.x; acc[1] += v0.y;
            } else {
                ushort4 u0 = *(const ushort4*)(X + (size_t)s0 * C + lane * VF);
                acc[0] += bf2f(u0.x); acc[1] += bf2f(u0.y);
                acc[2] += bf2f(u0.z); acc[3] += bf2f(u0.w);
            }
        }
    }

    ushort_t* o = T + (size_t)node * C + lane * VF;
    if constexpr (VF == 2) {
        ushort2 w;
        w.x = f2bf(acc[0]); w.y = f2bf(acc[1]);
        *(ushort2*)o = w;
    } else {
        ushort4 w;
        w.x = f2bf(acc[0]); w.y = f2bf(acc[1]);
        w.z = f2bf(acc[2]); w.w = f2bf(acc[3]);
        *(ushort4*)o = w;
    }
}

// ---- bf16 MFMA GEMM: C[M][N] = act(A @ W + bias), Wt[N][K] bf16, A bf16.
// BM=128, BN=128, BK=32, 2x2 waves. A/C not __restrict__ (GEMM4 is in-place;
// safe at gy=1: block owns full K-read + full N-write of its rows, and the
// final __syncthreads orders all its global A reads before epilogue stores).
template <bool RELU, typename OT>
__global__ __launch_bounds__(256) void gemm_kernel(
    const ushort_t* A, const ushort_t* __restrict__ Wt,
    const float* __restrict__ bias, OT* C, int M, int N, int K) {
    constexpr int BM = 128, BN = 128, BK = 32;
    constexpr int LDW = BK + 8;
    __shared__ ushort_t As[BM * LDW];
    __shared__ ushort_t Bs[BN * LDW];

    const int tid = threadIdx.x;
    const int lane = tid & 63;
    const int wid = tid >> 6;
    const int wm = wid & 1;
    const int wn = wid >> 1;
    const int l15 = lane & 15;
    const int q = lane >> 4;

    const int bm = blockIdx.x * BM;
    const int bn = blockIdx.y * BN;

    floatx4 acc[4][4];
#pragma unroll
    for (int mi = 0; mi < 4; ++mi)
#pragma unroll
        for (int ni = 0; ni < 4; ++ni) {
            floatx4 z = {0.f, 0.f, 0.f, 0.f};
            acc[mi][ni] = z;
        }

    for (int kt = 0; kt < K; kt += BK) {
#pragma unroll
        for (int p = 0; p < 4; ++p) {
            int i = p * 256 + tid;
            int row = i >> 3;
            int c4 = i & 7;
            int gr = bm + row;
            if (gr > M - 1) gr = M - 1;  // clamp stays inside this block's rows
            ushort4 u = *(const ushort4*)(A + (size_t)gr * K + kt + c4 * 4);
            *(ushort4*)&As[row * LDW + c4 * 4] = u;
        }
#pragma unroll
        for (int p = 0; p < 4; ++p) {
            int i = p * 256 + tid;
            int row = i >> 3;
            int c4 = i & 7;
            ushort4 u = *(const ushort4*)(Wt + (size_t)(bn + row) * K + kt + c4 * 4);
            *(ushort4*)&Bs[row * LDW + c4 * 4] = u;
        }
        __syncthreads();

        bf16x8 av[4], bv[4];
#pragma unroll
        for (int mi = 0; mi < 4; ++mi)
            av[mi] = *(const bf16x8*)&As[(wm * 64 + mi * 16 + l15) * LDW + q * 8];
#pragma unroll
        for (int ni = 0; ni < 4; ++ni)
            bv[ni] = *(const bf16x8*)&Bs[(wn * 64 + ni * 16 + l15) * LDW + q * 8];
#pragma unroll
        for (int mi = 0; mi < 4; ++mi)
#pragma unroll
            for (int ni = 0; ni < 4; ++ni)
                acc[mi][ni] = __builtin_amdgcn_mfma_f32_16x16x32_bf16(
                    av[mi], bv[ni], acc[mi][ni], 0, 0, 0);
        __syncthreads();
    }

    float bval[4];
#pragma unroll
    for (int ni = 0; ni < 4; ++ni) bval[ni] = bias[bn + wn * 64 + ni * 16 + l15];
#pragma unroll
    for (int mi = 0; mi < 4; ++mi) {
#pragma unroll
        for (int r = 0; r < 4; ++r) {
            int row = bm + wm * 64 + mi * 16 + q * 4 + r;
            if (row < M) {
#pragma unroll
                for (int ni = 0; ni < 4; ++ni) {
                    int col = bn + wn * 64 + ni * 16 + l15;
                    float v = acc[mi][ni][r] + bval[ni];
                    if (RELU) v = v > 0.f ? v : 0.f;
                    if constexpr (sizeof(OT) == 2)
                        C[(size_t)row * N + col] = f2bf(v);
                    else
                        C[(size_t)row * N + col] = v;
                }
            }
        }
    }
}

extern "C" void kernel_launch(void* const* d_in, const int* in_sizes, int n_in,
                              void* d_out, int out_size, void* d_ws, size_t ws_size,
                              hipStream_t stream) {
    const float* x   = (const float*)d_in[0];
    const int*   ei  = (const int*)d_in[1];
    const float* W1a = (const float*)d_in[2];
    const float* b1a = (const float*)d_in[3];
    const float* W2a = (const float*)d_in[4];
    const float* b2a = (const float*)d_in[5];
    const float* W1b = (const float*)d_in[6];
    const float* b1b = (const float*)d_in[7];
    const float* W2b = (const float*)d_in[8];
    const float* b2b = (const float*)d_in[9];
    const int* src = ei;
    const int* dst = ei + N_EDGES;
    float* out = (float*)d_out;

    // ---- workspace layout (~85MB; 103MB proven to fit) ----
    char* base = (char*)d_ws;
    size_t o = 0;
    ushort_t* wt1a = (ushort_t*)(base + o); o += 128 * 256 * 2;
    ushort_t* wt2a = (ushort_t*)(base + o); o += 256 * 256 * 2;
    ushort_t* wt1b = (ushort_t*)(base + o); o += 256 * 256 * 2;
    ushort_t* wt2b = (ushort_t*)(base + o); o += 256 * 128 * 2;
    o = (o + 255) & ~(size_t)255;
    int* deg     = (int*)(base + o); o += (size_t)N_NODES * 4;
    int* row_ptr = (int*)(base + o); o += (size_t)N_NODES * 4;
    int* cursor  = (int*)(base + o); o += (size_t)N_NODES * 4;
    int* bsum    = (int*)(base + o); o += 128 * 4;
    int* boff    = (int*)(base + o); o += 128 * 4;
    o = (o + 255) & ~(size_t)255;
    int* csr_src = (int*)(base + o); o += (size_t)N_EDGES * 4;
    o = (o + 255) & ~(size_t)255;
    ushort_t* t1   = (ushort_t*)(base + o); o += (size_t)N_NODES * 128 * 2;
    ushort_t* tbig = (ushort_t*)(base + o); o += (size_t)N_NODES * 256 * 2;  // u1, then t2
    (void)ws_size; (void)o; (void)in_sizes; (void)n_in; (void)out_size;

    ushort_t* inter = (ushort_t*)d_out;  // h, then u2 (bf16 N*256 in d_out)

    // ---- weights -> bf16 transposed (single launch) ----
    cvt_all_kernel<<<768, 256, 0, stream>>>(W1a, W2a, W1b, W2b,
                                            wt1a, wt2a, wt1b, wt2b);

    // ---- CSR build (bucketed hist/fill; reused by both layers) ----
    const int NB = (N_NODES + 1023) / 1024;  // 98
    hipMemsetAsync(deg, 0, (size_t)N_NODES * 4, stream);
    hist_kernel<<<dim3(1024, NBUCK), 256, 0, stream>>>(src, dst, deg, N_EDGES);
    scan1_kernel<<<NB, 256, 0, stream>>>(deg, bsum, N_NODES);
    scan2_kernel<<<1, 128, 0, stream>>>(bsum, boff, NB);
    scan3_kernel<<<NB, 256, 0, stream>>>(deg, boff, row_ptr, cursor, N_NODES);
    fill_kernel<<<dim3(1024, NBUCK), 256, 0, stream>>>(src, dst, cursor, csr_src,
                                                       N_EDGES);

    const int gm = (N_NODES + 127) / 128;    // 782
    const int ga = (N_NODES + 3) / 4;        // 25000

    // ---- layer 1 ----
    agg_gather_kernel<128, float><<<ga, 256, 0, stream>>>(x, t1, row_ptr, deg,
                                                          csr_src, N_NODES);
    // u1 = relu(t1 @ W1a + b1a)   (ws -> ws)
    gemm_kernel<true, ushort_t><<<dim3(gm, 2), 256, 0, stream>>>(
        t1, wt1a, b1a, tbig, N_NODES, 256, 128);
    // h = relu(u1 @ W2a + b2a)    (ws -> d_out, no alias)
    gemm_kernel<true, ushort_t><<<dim3(gm, 2), 256, 0, stream>>>(
        tbig, wt2a, b2a, inter, N_NODES, 256, 256);

    // ---- layer 2 ----
    // t2 = h + segsum(h)          (d_out -> ws, overwrites dead u1)
    agg_gather_kernel<256, ushort_t><<<ga, 256, 0, stream>>>(inter, tbig, row_ptr,
                                                             deg, csr_src, N_NODES);
    // u2 = relu(t2 @ W1b + b1b)   (ws -> d_out, overwrites dead h)
    gemm_kernel<true, ushort_t><<<dim3(gm, 2), 256, 0, stream>>>(
        tbig, wt1b, b1b, inter, N_NODES, 256, 256);
    // out = u2 @ W2b + b2b        (in-place in d_out, gy=1, equal 512B row extents)
    gemm_kernel<false, float><<<dim3(gm, 1), 256, 0, stream>>>(
        inter, wt2b, b2b, out, N_NODES, 128, 256);
}

// Round 6
// 590.819 us; speedup vs baseline: 14.0220x; 1.0603x over previous
//
#include <hip/hip_runtime.h>

// ---------------------------------------------------------------------------
// GIN 2-layer: out = gin_conv2( relu(gin_conv1(x)) )
// N=100000 nodes, E=1.6M edges, C: 128 -> 256 -> 256 -> 128
// R6 (from R5 @ 626us; agg_gather 2x120us latency-bound: HBM 48%, VALU 28%):
//  - agg_gather widened: lane loads 16B (8 bf16), G=C/8 lanes per neighbor,
//    64/G neighbors per wave-step, x4 unroll -> 4KB in flight/wave (2x R5),
//    half the load instructions. shfl_xor cross-sub reduction at the end.
//  - x pre-converted to bf16 (xb in d_out; dead after agg1, overwritten by
//    GEMM2) -> layer-1 gather bytes halved. ws stays ~85MB (proven).
//  - CSR build (bucketed hist/fill + 3-kernel scan) and GEMMs unchanged.
// ---------------------------------------------------------------------------

#define N_NODES 100000
#define N_EDGES 1600000
#define NBUCK 13  // buckets = dst >> 13 -> 0..12

typedef unsigned short ushort_t;
typedef short bf16x8 __attribute__((ext_vector_type(8)));
typedef float floatx4 __attribute__((ext_vector_type(4)));

static __device__ __forceinline__ ushort_t f2bf(float f) {
    unsigned u = __float_as_uint(f);
    u = (u + 0x7FFFu + ((u >> 16) & 1u)) >> 16;
    return (ushort_t)u;
}
static __device__ __forceinline__ unsigned pack2bf(float lo, float hi) {
    return (unsigned)f2bf(lo) | ((unsigned)f2bf(hi) << 16);
}
// accumulate 8 bf16 (as uint4) into 8 f32
static __device__ __forceinline__ void addu4(float* acc, const uint4 v) {
    const unsigned w0 = v.x, w1 = v.y, w2 = v.z, w3 = v.w;
    acc[0] += __uint_as_float(w0 << 16);
    acc[1] += __uint_as_float(w0 & 0xFFFF0000u);
    acc[2] += __uint_as_float(w1 << 16);
    acc[3] += __uint_as_float(w1 & 0xFFFF0000u);
    acc[4] += __uint_as_float(w2 << 16);
    acc[5] += __uint_as_float(w2 & 0xFFFF0000u);
    acc[6] += __uint_as_float(w3 << 16);
    acc[7] += __uint_as_float(w3 & 0xFFFF0000u);
}

// ---- x (f32) -> bf16, 8 elems/thread ----
__global__ __launch_bounds__(256) void cvt_x_kernel(const float* __restrict__ X,
                                                    ushort_t* __restrict__ Xb, int n8) {
    int i = blockIdx.x * 256 + threadIdx.x;
    if (i < n8) {
        const float4 a = ((const float4*)X)[2 * i];
        const float4 b = ((const float4*)X)[2 * i + 1];
        uint4 r;
        r.x = pack2bf(a.x, a.y);
        r.y = pack2bf(a.z, a.w);
        r.z = pack2bf(b.x, b.y);
        r.w = pack2bf(b.z, b.w);
        ((uint4*)Xb)[i] = r;
    }
}

// ---- all four weights -> bf16 transposed, one launch ----
__global__ __launch_bounds__(256) void cvt_all_kernel(
    const float* __restrict__ W1a, const float* __restrict__ W2a,
    const float* __restrict__ W1b, const float* __restrict__ W2b,
    ushort_t* __restrict__ wt1a, ushort_t* __restrict__ wt2a,
    ushort_t* __restrict__ wt1b, ushort_t* __restrict__ wt2b) {
    int i = blockIdx.x * 256 + threadIdx.x;
    if (i < 32768) {                       // W1a [128][256]
        int k = i >> 8, n = i & 255;
        wt1a[n * 128 + k] = f2bf(W1a[i]);
    } else if (i < 98304) {                // W2a [256][256]
        int j = i - 32768, k = j >> 8, n = j & 255;
        wt2a[n * 256 + k] = f2bf(W2a[j]);
    } else if (i < 163840) {               // W1b [256][256]
        int j = i - 98304, k = j >> 8, n = j & 255;
        wt1b[n * 256 + k] = f2bf(W1b[j]);
    } else if (i < 196608) {               // W2b [256][128]
        int j = i - 163840, k = j >> 7, n = j & 127;
        wt2b[n * 256 + k] = f2bf(W2b[j]);
    }
}

// ---- CSR build, bucketed: blockIdx.y owns dst range [y<<13, (y+1)<<13) ----
__global__ __launch_bounds__(256) void hist_kernel(const int* __restrict__ src,
                                                   const int* __restrict__ dst,
                                                   int* __restrict__ deg, int nE) {
    const int bucket = blockIdx.y;
    for (int e = blockIdx.x * 256 + threadIdx.x; e < nE; e += gridDim.x * 256) {
        int d = dst[e];
        int s = src[e];
        if ((unsigned)d < (unsigned)N_NODES && (unsigned)s < (unsigned)N_NODES &&
            (d >> 13) == bucket)
            atomicAdd(&deg[d], 1);
    }
}

__global__ __launch_bounds__(256) void fill_kernel(const int* __restrict__ src,
                                                   const int* __restrict__ dst,
                                                   int* __restrict__ cursor,
                                                   int* __restrict__ csr_src, int nE) {
    const int bucket = blockIdx.y;
    for (int e = blockIdx.x * 256 + threadIdx.x; e < nE; e += gridDim.x * 256) {
        int d = dst[e];
        int s = src[e];
        if ((unsigned)d < (unsigned)N_NODES && (unsigned)s < (unsigned)N_NODES &&
            (d >> 13) == bucket) {
            int pos = atomicAdd(&cursor[d], 1);
            csr_src[pos] = s;
        }
    }
}

// ---- scan: deg -> row_ptr (exclusive), cursor copy ----
__global__ __launch_bounds__(256) void scan1_kernel(const int* __restrict__ deg,
                                                    int* __restrict__ bsum, int n) {
    __shared__ int l[256];
    int b = blockIdx.x, t = threadIdx.x;
    int base = b * 1024 + t * 4;
    int s = 0;
#pragma unroll
    for (int k = 0; k < 4; ++k) {
        int i = base + k;
        if (i < n) s += deg[i];
    }
    l[t] = s;
    __syncthreads();
    for (int off = 128; off > 0; off >>= 1) {
        if (t < off) l[t] += l[t + off];
        __syncthreads();
    }
    if (t == 0) bsum[b] = l[0];
}

__global__ __launch_bounds__(128) void scan2_kernel(const int* __restrict__ bsum,
                                                    int* __restrict__ boff, int nb) {
    __shared__ int l[128];
    int t = threadIdx.x;
    int v = (t < nb) ? bsum[t] : 0;
    l[t] = v;
    __syncthreads();
    for (int off = 1; off < 128; off <<= 1) {
        int add = (t >= off) ? l[t - off] : 0;
        __syncthreads();
        l[t] += add;
        __syncthreads();
    }
    if (t < nb) boff[t] = l[t] - v;  // exclusive
}

__global__ __launch_bounds__(256) void scan3_kernel(const int* __restrict__ deg,
                                                    const int* __restrict__ boff,
                                                    int* __restrict__ row_ptr,
                                                    int* __restrict__ cursor, int n) {
    __shared__ int l[256];
    int b = blockIdx.x, t = threadIdx.x;
    int base = b * 1024 + t * 4;
    int d[4];
    int s = 0;
#pragma unroll
    for (int k = 0; k < 4; ++k) {
        int i = base + k;
        d[k] = (i < n) ? deg[i] : 0;
        s += d[k];
    }
    l[t] = s;
    __syncthreads();
    for (int off = 1; off < 256; off <<= 1) {
        int add = (t >= off) ? l[t - off] : 0;
        __syncthreads();
        l[t] += add;
        __syncthreads();
    }
    int run = boff[b] + l[t] - s;
#pragma unroll
    for (int k = 0; k < 4; ++k) {
        int i = base + k;
        if (i < n) {
            row_ptr[i] = run;
            cursor[i] = run;
        }
        run += d[k];
    }
}

// ---- per-node gather: T[i] = X[i] + sum_{j in N(i)} X[j]  (bf16 in/out) ----
// Lane loads 16B (8 bf16). G=C/8 lanes cover a row; NPW=64/G neighbors per
// wave-step; x4 unroll -> 4*NPW neighbors (4KB) in flight per wave.
template <int C>
__global__ __launch_bounds__(256) void agg_gather_kernel(
    const ushort_t* __restrict__ X, ushort_t* __restrict__ T,
    const int* __restrict__ row_ptr, const int* __restrict__ deg,
    const int* __restrict__ csr_src, int nN) {
    constexpr int G = C / 8;      // lanes per neighbor row
    constexpr int NPW = 64 / G;   // neighbors per wave-step (2 or 4)
    const int lane = threadIdx.x & 63;
    const int wid = threadIdx.x >> 6;
    const int node = blockIdx.x * 4 + wid;
    if (node >= nN) return;
    const int sub = lane / G;
    const size_t coff = (size_t)(lane % G) * 8;

    float acc[8];
#pragma unroll
    for (int k = 0; k < 8; ++k) acc[k] = 0.f;

    const int base = row_ptr[node];
    const int dg = deg[node];
    for (int j0 = 0; j0 < dg; j0 += 64) {
        int cnt = dg - j0;
        if (cnt > 64) cnt = 64;
        int nidx = 0;
        if (lane < cnt) nidx = csr_src[base + j0 + lane];
        if ((unsigned)nidx >= (unsigned)N_NODES) nidx = 0;  // safety clamp
        int j = 0;
        for (; j + 4 * NPW <= cnt; j += 4 * NPW) {
            uint4 v[4];
#pragma unroll
            for (int u = 0; u < 4; ++u) {
                int idx = __shfl(nidx, j + u * NPW + sub);
                v[u] = *(const uint4*)(X + (size_t)idx * C + coff);
            }
#pragma unroll
            for (int u = 0; u < 4; ++u) addu4(acc, v[u]);
        }
        for (; j < cnt; j += NPW) {
            int jj = j + sub;
            int srcl = (jj < cnt) ? jj : (cnt - 1);  // keep shfl src in range
            int idx = __shfl(nidx, srcl);
            if (jj < cnt) {
                uint4 v = *(const uint4*)(X + (size_t)idx * C + coff);
                addu4(acc, v);
            }
        }
    }
    // self term, sub-group 0 only (others would double-count after reduction)
    if (sub == 0) {
        uint4 v = *(const uint4*)(X + (size_t)node * C + coff);
        addu4(acc, v);
    }
    // reduce partials across sub-groups
#pragma unroll
    for (int off = G; off < 64; off <<= 1)
#pragma unroll
        for (int k = 0; k < 8; ++k) acc[k] += __shfl_xor(acc[k], off);

    if (lane < G) {
        uint4 r;
        r.x = pack2bf(acc[0], acc[1]);
        r.y = pack2bf(acc[2], acc[3]);
        r.z = pack2bf(acc[4], acc[5]);
        r.w = pack2bf(acc[6], acc[7]);
        *(uint4*)(T + (size_t)node * C + coff) = r;
    }
}

// ---- bf16 MFMA GEMM: C[M][N] = act(A @ W + bias), Wt[N][K] bf16, A bf16.
// BM=128, BN=128, BK=32, 2x2 waves. A/C not __restrict__ (GEMM4 is in-place;
// safe at gy=1: block owns full K-read + full N-write of its rows).
template <bool RELU, typename OT>
__global__ __launch_bounds__(256) void gemm_kernel(
    const ushort_t* A, const ushort_t* __restrict__ Wt,
    const float* __restrict__ bias, OT* C, int M, int N, int K) {
    constexpr int BM = 128, BN = 128, BK = 32;
    constexpr int LDW = BK + 8;
    __shared__ ushort_t As[BM * LDW];
    __shared__ ushort_t Bs[BN * LDW];

    const int tid = threadIdx.x;
    const int lane = tid & 63;
    const int wid = tid >> 6;
    const int wm = wid & 1;
    const int wn = wid >> 1;
    const int l15 = lane & 15;
    const int q = lane >> 4;

    const int bm = blockIdx.x * BM;
    const int bn = blockIdx.y * BN;

    floatx4 acc[4][4];
#pragma unroll
    for (int mi = 0; mi < 4; ++mi)
#pragma unroll
        for (int ni = 0; ni < 4; ++ni) {
            floatx4 z = {0.f, 0.f, 0.f, 0.f};
            acc[mi][ni] = z;
        }

    for (int kt = 0; kt < K; kt += BK) {
#pragma unroll
        for (int p = 0; p < 4; ++p) {
            int i = p * 256 + tid;
            int row = i >> 3;
            int c4 = i & 7;
            int gr = bm + row;
            if (gr > M - 1) gr = M - 1;  // clamp stays inside this block's rows
            ushort4 u = *(const ushort4*)(A + (size_t)gr * K + kt + c4 * 4);
            *(ushort4*)&As[row * LDW + c4 * 4] = u;
        }
#pragma unroll
        for (int p = 0; p < 4; ++p) {
            int i = p * 256 + tid;
            int row = i >> 3;
            int c4 = i & 7;
            ushort4 u = *(const ushort4*)(Wt + (size_t)(bn + row) * K + kt + c4 * 4);
            *(ushort4*)&Bs[row * LDW + c4 * 4] = u;
        }
        __syncthreads();

        bf16x8 av[4], bv[4];
#pragma unroll
        for (int mi = 0; mi < 4; ++mi)
            av[mi] = *(const bf16x8*)&As[(wm * 64 + mi * 16 + l15) * LDW + q * 8];
#pragma unroll
        for (int ni = 0; ni < 4; ++ni)
            bv[ni] = *(const bf16x8*)&Bs[(wn * 64 + ni * 16 + l15) * LDW + q * 8];
#pragma unroll
        for (int mi = 0; mi < 4; ++mi)
#pragma unroll
            for (int ni = 0; ni < 4; ++ni)
                acc[mi][ni] = __builtin_amdgcn_mfma_f32_16x16x32_bf16(
                    av[mi], bv[ni], acc[mi][ni], 0, 0, 0);
        __syncthreads();
    }

    float bval[4];
#pragma unroll
    for (int ni = 0; ni < 4; ++ni) bval[ni] = bias[bn + wn * 64 + ni * 16 + l15];
#pragma unroll
    for (int mi = 0; mi < 4; ++mi) {
#pragma unroll
        for (int r = 0; r < 4; ++r) {
            int row = bm + wm * 64 + mi * 16 + q * 4 + r;
            if (row < M) {
#pragma unroll
                for (int ni = 0; ni < 4; ++ni) {
                    int col = bn + wn * 64 + ni * 16 + l15;
                    float v = acc[mi][ni][r] + bval[ni];
                    if (RELU) v = v > 0.f ? v : 0.f;
                    if constexpr (sizeof(OT) == 2)
                        C[(size_t)row * N + col] = f2bf(v);
                    else
                        C[(size_t)row * N + col] = v;
                }
            }
        }
    }
}

extern "C" void kernel_launch(void* const* d_in, const int* in_sizes, int n_in,
                              void* d_out, int out_size, void* d_ws, size_t ws_size,
                              hipStream_t stream) {
    const float* x   = (const float*)d_in[0];
    const int*   ei  = (const int*)d_in[1];
    const float* W1a = (const float*)d_in[2];
    const float* b1a = (const float*)d_in[3];
    const float* W2a = (const float*)d_in[4];
    const float* b2a = (const float*)d_in[5];
    const float* W1b = (const float*)d_in[6];
    const float* b1b = (const float*)d_in[7];
    const float* W2b = (const float*)d_in[8];
    const float* b2b = (const float*)d_in[9];
    const int* src = ei;
    const int* dst = ei + N_EDGES;
    float* out = (float*)d_out;

    // ---- workspace layout (~85MB; 103MB proven to fit) ----
    char* base = (char*)d_ws;
    size_t o = 0;
    ushort_t* wt1a = (ushort_t*)(base + o); o += 128 * 256 * 2;
    ushort_t* wt2a = (ushort_t*)(base + o); o += 256 * 256 * 2;
    ushort_t* wt1b = (ushort_t*)(base + o); o += 256 * 256 * 2;
    ushort_t* wt2b = (ushort_t*)(base + o); o += 256 * 128 * 2;
    o = (o + 255) & ~(size_t)255;
    int* deg     = (int*)(base + o); o += (size_t)N_NODES * 4;
    int* row_ptr = (int*)(base + o); o += (size_t)N_NODES * 4;
    int* cursor  = (int*)(base + o); o += (size_t)N_NODES * 4;
    int* bsum    = (int*)(base + o); o += 128 * 4;
    int* boff    = (int*)(base + o); o += 128 * 4;
    o = (o + 255) & ~(size_t)255;
    int* csr_src = (int*)(base + o); o += (size_t)N_EDGES * 4;
    o = (o + 255) & ~(size_t)255;
    ushort_t* t1   = (ushort_t*)(base + o); o += (size_t)N_NODES * 128 * 2;
    ushort_t* tbig = (ushort_t*)(base + o); o += (size_t)N_NODES * 256 * 2;  // u1, then t2
    (void)ws_size; (void)o; (void)in_sizes; (void)n_in; (void)out_size;

    ushort_t* inter = (ushort_t*)d_out;  // xb, then h, then u2 (d_out = 51.2MB)
    ushort_t* xb    = (ushort_t*)d_out;  // bf16 x, dead after agg1 (GEMM2 overwrites)

    // ---- weights -> bf16 transposed; x -> bf16 ----
    cvt_all_kernel<<<768, 256, 0, stream>>>(W1a, W2a, W1b, W2b,
                                            wt1a, wt2a, wt1b, wt2b);
    cvt_x_kernel<<<(N_NODES * 128 / 8 + 255) / 256, 256, 0, stream>>>(
        x, xb, N_NODES * 128 / 8);

    // ---- CSR build (bucketed hist/fill; reused by both layers) ----
    const int NB = (N_NODES + 1023) / 1024;  // 98
    hipMemsetAsync(deg, 0, (size_t)N_NODES * 4, stream);
    hist_kernel<<<dim3(1024, NBUCK), 256, 0, stream>>>(src, dst, deg, N_EDGES);
    scan1_kernel<<<NB, 256, 0, stream>>>(deg, bsum, N_NODES);
    scan2_kernel<<<1, 128, 0, stream>>>(bsum, boff, NB);
    scan3_kernel<<<NB, 256, 0, stream>>>(deg, boff, row_ptr, cursor, N_NODES);
    fill_kernel<<<dim3(1024, NBUCK), 256, 0, stream>>>(src, dst, cursor, csr_src,
                                                       N_EDGES);

    const int gm = (N_NODES + 127) / 128;    // 782
    const int ga = (N_NODES + 3) / 4;        // 25000

    // ---- layer 1 ----
    // t1 = xb + segsum(xb)        (d_out -> ws)
    agg_gather_kernel<128><<<ga, 256, 0, stream>>>(xb, t1, row_ptr, deg,
                                                   csr_src, N_NODES);
    // u1 = relu(t1 @ W1a + b1a)   (ws -> ws)
    gemm_kernel<true, ushort_t><<<dim3(gm, 2), 256, 0, stream>>>(
        t1, wt1a, b1a, tbig, N_NODES, 256, 128);
    // h = relu(u1 @ W2a + b2a)    (ws -> d_out, overwrites dead xb)
    gemm_kernel<true, ushort_t><<<dim3(gm, 2), 256, 0, stream>>>(
        tbig, wt2a, b2a, inter, N_NODES, 256, 256);

    // ---- layer 2 ----
    // t2 = h + segsum(h)          (d_out -> ws, overwrites dead u1)
    agg_gather_kernel<256><<<ga, 256, 0, stream>>>(inter, tbig, row_ptr,
                                                   deg, csr_src, N_NODES);
    // u2 = relu(t2 @ W1b + b1b)   (ws -> d_out, overwrites dead h)
    gemm_kernel<true, ushort_t><<<dim3(gm, 2), 256, 0, stream>>>(
        tbig, wt1b, b1b, inter, N_NODES, 256, 256);
    // out = u2 @ W2b + b2b        (in-place in d_out, gy=1, equal 512B row extents)
    gemm_kernel<false, float><<<dim3(gm, 1), 256, 0, stream>>>(
        inter, wt2b, b2b, out, N_NODES, 128, 256);
}

// Round 7
// 578.127 us; speedup vs baseline: 14.3298x; 1.0220x over previous
//
#include <hip/hip_runtime.h>

// ---------------------------------------------------------------------------
// GIN 2-layer: out = gin_conv2( relu(gin_conv1(x)) )
// N=100000 nodes, E=1.6M edges, C: 128 -> 256 -> 256 -> 128
// R7 (from R6 @ 591us):
//  - agg_gather: fully-predicated 16-neighbor batches, NO serial remainder
//    (R6's tail loop serialized ~half the avg-degree-16 row). Invalid slots
//    load a zeroed ws row via pointer-select; all U loads issue before any
//    accumulate -> U*16B in flight per lane (U=8 for C=256, 4 for C=128).
//  - GEMM: m97-style staging - unpadded [row][BK] LDS, A and B staged with
//    __builtin_amdgcn_global_load_lds width=16 (lane l -> base + l*16, exact
//    row-major match). Per-lane gr<M exec guard avoids OOB on last block.
//    Frag reads ds_read_b128 at row*64 + q*16; final __syncthreads drains
//    vmcnt(0) so in-place GEMM4 stays safe.
//  - CSR build (bucketed hist/fill + 3-kernel scan), cvt kernels unchanged.
// ---------------------------------------------------------------------------

#define N_NODES 100000
#define N_EDGES 1600000
#define NBUCK 13  // buckets = dst >> 13 -> 0..12

typedef unsigned short ushort_t;
typedef short bf16x8 __attribute__((ext_vector_type(8)));
typedef float floatx4 __attribute__((ext_vector_type(4)));

static __device__ __forceinline__ ushort_t f2bf(float f) {
    unsigned u = __float_as_uint(f);
    u = (u + 0x7FFFu + ((u >> 16) & 1u)) >> 16;
    return (ushort_t)u;
}
static __device__ __forceinline__ unsigned pack2bf(float lo, float hi) {
    return (unsigned)f2bf(lo) | ((unsigned)f2bf(hi) << 16);
}
// accumulate 8 bf16 (as uint4) into 8 f32
static __device__ __forceinline__ void addu4(float* acc, const uint4 v) {
    const unsigned w0 = v.x, w1 = v.y, w2 = v.z, w3 = v.w;
    acc[0] += __uint_as_float(w0 << 16);
    acc[1] += __uint_as_float(w0 & 0xFFFF0000u);
    acc[2] += __uint_as_float(w1 << 16);
    acc[3] += __uint_as_float(w1 & 0xFFFF0000u);
    acc[4] += __uint_as_float(w2 << 16);
    acc[5] += __uint_as_float(w2 & 0xFFFF0000u);
    acc[6] += __uint_as_float(w3 << 16);
    acc[7] += __uint_as_float(w3 & 0xFFFF0000u);
}

#define GLOAD_LDS16(g, l)                                                     \
    __builtin_amdgcn_global_load_lds(                                         \
        (const __attribute__((address_space(1))) void*)(g),                   \
        (__attribute__((address_space(3))) void*)(l), 16, 0, 0)

// ---- x (f32) -> bf16, 8 elems/thread ----
__global__ __launch_bounds__(256) void cvt_x_kernel(const float* __restrict__ X,
                                                    ushort_t* __restrict__ Xb, int n8) {
    int i = blockIdx.x * 256 + threadIdx.x;
    if (i < n8) {
        const float4 a = ((const float4*)X)[2 * i];
        const float4 b = ((const float4*)X)[2 * i + 1];
        uint4 r;
        r.x = pack2bf(a.x, a.y);
        r.y = pack2bf(a.z, a.w);
        r.z = pack2bf(b.x, b.y);
        r.w = pack2bf(b.z, b.w);
        ((uint4*)Xb)[i] = r;
    }
}

// ---- all four weights -> bf16 transposed, one launch ----
__global__ __launch_bounds__(256) void cvt_all_kernel(
    const float* __restrict__ W1a, const float* __restrict__ W2a,
    const float* __restrict__ W1b, const float* __restrict__ W2b,
    ushort_t* __restrict__ wt1a, ushort_t* __restrict__ wt2a,
    ushort_t* __restrict__ wt1b, ushort_t* __restrict__ wt2b) {
    int i = blockIdx.x * 256 + threadIdx.x;
    if (i < 32768) {                       // W1a [128][256]
        int k = i >> 8, n = i & 255;
        wt1a[n * 128 + k] = f2bf(W1a[i]);
    } else if (i < 98304) {                // W2a [256][256]
        int j = i - 32768, k = j >> 8, n = j & 255;
        wt2a[n * 256 + k] = f2bf(W2a[j]);
    } else if (i < 163840) {               // W1b [256][256]
        int j = i - 98304, k = j >> 8, n = j & 255;
        wt1b[n * 256 + k] = f2bf(W1b[j]);
    } else if (i < 196608) {               // W2b [256][128]
        int j = i - 163840, k = j >> 7, n = j & 127;
        wt2b[n * 256 + k] = f2bf(W2b[j]);
    }
}

// ---- CSR build, bucketed: blockIdx.y owns dst range [y<<13, (y+1)<<13) ----
__global__ __launch_bounds__(256) void hist_kernel(const int* __restrict__ src,
                                                   const int* __restrict__ dst,
                                                   int* __restrict__ deg, int nE) {
    const int bucket = blockIdx.y;
    for (int e = blockIdx.x * 256 + threadIdx.x; e < nE; e += gridDim.x * 256) {
        int d = dst[e];
        int s = src[e];
        if ((unsigned)d < (unsigned)N_NODES && (unsigned)s < (unsigned)N_NODES &&
            (d >> 13) == bucket)
            atomicAdd(&deg[d], 1);
    }
}

__global__ __launch_bounds__(256) void fill_kernel(const int* __restrict__ src,
                                                   const int* __restrict__ dst,
                                                   int* __restrict__ cursor,
                                                   int* __restrict__ csr_src, int nE) {
    const int bucket = blockIdx.y;
    for (int e = blockIdx.x * 256 + threadIdx.x; e < nE; e += gridDim.x * 256) {
        int d = dst[e];
        int s = src[e];
        if ((unsigned)d < (unsigned)N_NODES && (unsigned)s < (unsigned)N_NODES &&
            (d >> 13) == bucket) {
            int pos = atomicAdd(&cursor[d], 1);
            csr_src[pos] = s;
        }
    }
}

// ---- scan: deg -> row_ptr (exclusive), cursor copy ----
__global__ __launch_bounds__(256) void scan1_kernel(const int* __restrict__ deg,
                                                    int* __restrict__ bsum, int n) {
    __shared__ int l[256];
    int b = blockIdx.x, t = threadIdx.x;
    int base = b * 1024 + t * 4;
    int s = 0;
#pragma unroll
    for (int k = 0; k < 4; ++k) {
        int i = base + k;
        if (i < n) s += deg[i];
    }
    l[t] = s;
    __syncthreads();
    for (int off = 128; off > 0; off >>= 1) {
        if (t < off) l[t] += l[t + off];
        __syncthreads();
    }
    if (t == 0) bsum[b] = l[0];
}

__global__ __launch_bounds__(128) void scan2_kernel(const int* __restrict__ bsum,
                                                    int* __restrict__ boff, int nb) {
    __shared__ int l[128];
    int t = threadIdx.x;
    int v = (t < nb) ? bsum[t] : 0;
    l[t] = v;
    __syncthreads();
    for (int off = 1; off < 128; off <<= 1) {
        int add = (t >= off) ? l[t - off] : 0;
        __syncthreads();
        l[t] += add;
        __syncthreads();
    }
    if (t < nb) boff[t] = l[t] - v;  // exclusive
}

__global__ __launch_bounds__(256) void scan3_kernel(const int* __restrict__ deg,
                                                    const int* __restrict__ boff,
                                                    int* __restrict__ row_ptr,
                                                    int* __restrict__ cursor, int n) {
    __shared__ int l[256];
    int b = blockIdx.x, t = threadIdx.x;
    int base = b * 1024 + t * 4;
    int d[4];
    int s = 0;
#pragma unroll
    for (int k = 0; k < 4; ++k) {
        int i = base + k;
        d[k] = (i < n) ? deg[i] : 0;
        s += d[k];
    }
    l[t] = s;
    __syncthreads();
    for (int off = 1; off < 256; off <<= 1) {
        int add = (t >= off) ? l[t - off] : 0;
        __syncthreads();
        l[t] += add;
        __syncthreads();
    }
    int run = boff[b] + l[t] - s;
#pragma unroll
    for (int k = 0; k < 4; ++k) {
        int i = base + k;
        if (i < n) {
            row_ptr[i] = run;
            cursor[i] = run;
        }
        run += d[k];
    }
}

// ---- per-node gather: T[i] = X[i] + sum_{j in N(i)} X[j]  (bf16 in/out) ----
// Lane loads 16B. G=C/8 lanes per neighbor row, NPW=64/G neighbors per step.
// Fully-predicated batches of U*NPW=16 neighbors: invalid slots load zrow
// (zeroed 512B ws row) -> no serial remainder, U loads in flight per lane.
template <int C, int U>
__global__ __launch_bounds__(256) void agg_gather_kernel(
    const ushort_t* __restrict__ X, ushort_t* __restrict__ T,
    const int* __restrict__ row_ptr, const int* __restrict__ deg,
    const int* __restrict__ csr_src, const ushort_t* __restrict__ zrow, int nN) {
    constexpr int G = C / 8;      // lanes per neighbor row (16 or 32)
    constexpr int NPW = 64 / G;   // neighbors per wave-step (4 or 2)
    constexpr int B = U * NPW;    // neighbors per batch (16)
    const int lane = threadIdx.x & 63;
    const int wid = threadIdx.x >> 6;
    const int node = blockIdx.x * 4 + wid;
    if (node >= nN) return;
    const int sub = lane / G;
    const int coff = (lane % G) * 8;  // ushort offset into row

    float acc[8];
#pragma unroll
    for (int k = 0; k < 8; ++k) acc[k] = 0.f;

    const int base = row_ptr[node];
    const int dg = deg[node];
    for (int j0 = 0; j0 < dg; j0 += 64) {
        int cnt = dg - j0;
        if (cnt > 64) cnt = 64;
        int nidx = (lane < cnt) ? csr_src[base + j0 + lane] : 0;
        if ((unsigned)nidx >= (unsigned)N_NODES) nidx = 0;  // safety clamp
        for (int j = 0; j < cnt; j += B) {
            uint4 v[U];
#pragma unroll
            for (int u = 0; u < U; ++u) {
                int jj = j + u * NPW + sub;
                bool ok = jj < cnt;
                int idx = __shfl(nidx, ok ? jj : 0);
                const ushort_t* p = ok ? (X + (size_t)idx * C) : zrow;
                v[u] = *(const uint4*)(p + coff);
            }
#pragma unroll
            for (int u = 0; u < U; ++u) addu4(acc, v[u]);
        }
    }
    // self term (sub-group 0 only; others would double-count after reduction)
    if (sub == 0) {
        uint4 v = *(const uint4*)(X + (size_t)node * C + coff);
        addu4(acc, v);
    }
    // reduce partials across sub-groups
#pragma unroll
    for (int off = G; off < 64; off <<= 1)
#pragma unroll
        for (int k = 0; k < 8; ++k) acc[k] += __shfl_xor(acc[k], off);

    if (lane < G) {
        uint4 r;
        r.x = pack2bf(acc[0], acc[1]);
        r.y = pack2bf(acc[2], acc[3]);
        r.z = pack2bf(acc[4], acc[5]);
        r.w = pack2bf(acc[6], acc[7]);
        *(uint4*)(T + (size_t)node * C + coff) = r;
    }
}

// ---- bf16 MFMA GEMM: C[M][N] = act(A @ W + bias), Wt[N][K] bf16, A bf16.
// m97-style: unpadded [row][BK] LDS, A/B staged via global_load_lds width=16
// (lane l -> LDS base + l*16 == row-major (l>>2)*64+(l&3)*16). Per-lane gr<M
// exec guard for the A tail (no OOB reads). A/C not __restrict__ (GEMM4 is
// in-place; safe at gy=1 - final __syncthreads drains vmcnt before stores).
template <bool RELU, typename OT>
__global__ __launch_bounds__(256) void gemm_kernel(
    const ushort_t* A, const ushort_t* __restrict__ Wt,
    const float* __restrict__ bias, OT* C, int M, int N, int K) {
    constexpr int BM = 128, BN = 128, BK = 32;
    __shared__ ushort_t As[BM * BK];
    __shared__ ushort_t Bs[BN * BK];

    const int tid = threadIdx.x;
    const int lane = tid & 63;
    const int wid = tid >> 6;
    const int wm = wid & 1;
    const int wn = wid >> 1;
    const int l15 = lane & 15;
    const int q = lane >> 4;
    const int srow = lane >> 2;        // 0..15: row within 16-row DMA group
    const int scol = (lane & 3) * 8;   // ushort offset within 64B row

    const int bm = blockIdx.x * BM;
    const int bn = blockIdx.y * BN;

    floatx4 acc[4][4];
#pragma unroll
    for (int mi = 0; mi < 4; ++mi)
#pragma unroll
        for (int ni = 0; ni < 4; ++ni) {
            floatx4 z = {0.f, 0.f, 0.f, 0.f};
            acc[mi][ni] = z;
        }

    for (int kt = 0; kt < K; kt += BK) {
        // wave wid stages rows [wid*32, wid*32+32) of both tiles, 16 rows/issue
#pragma unroll
        for (int half = 0; half < 2; ++half) {
            const int row = wid * 32 + half * 16 + srow;
            const int gr = bm + row;
            const ushort_t* gpa = A + (size_t)gr * K + kt + scol;
            ushort_t* lpa = &As[(wid * 32 + half * 16) * BK];  // wave-uniform
            if (gr < M) GLOAD_LDS16(gpa, lpa);
            const ushort_t* gpb = Wt + (size_t)(bn + row) * K + kt + scol;
            ushort_t* lpb = &Bs[(wid * 32 + half * 16) * BK];  // wave-uniform
            GLOAD_LDS16(gpb, lpb);
        }
        __syncthreads();  // drains vmcnt(0): DMA complete, LDS consistent

        bf16x8 av[4], bv[4];
#pragma unroll
        for (int mi = 0; mi < 4; ++mi)
            av[mi] = *(const bf16x8*)&As[(wm * 64 + mi * 16 + l15) * BK + q * 8];
#pragma unroll
        for (int ni = 0; ni < 4; ++ni)
            bv[ni] = *(const bf16x8*)&Bs[(wn * 64 + ni * 16 + l15) * BK + q * 8];
#pragma unroll
        for (int mi = 0; mi < 4; ++mi)
#pragma unroll
            for (int ni = 0; ni < 4; ++ni)
                acc[mi][ni] = __builtin_amdgcn_mfma_f32_16x16x32_bf16(
                    av[mi], bv[ni], acc[mi][ni], 0, 0, 0);
        __syncthreads();
    }

    float bval[4];
#pragma unroll
    for (int ni = 0; ni < 4; ++ni) bval[ni] = bias[bn + wn * 64 + ni * 16 + l15];
#pragma unroll
    for (int mi = 0; mi < 4; ++mi) {
#pragma unroll
        for (int r = 0; r < 4; ++r) {
            int row = bm + wm * 64 + mi * 16 + q * 4 + r;
            if (row < M) {
#pragma unroll
                for (int ni = 0; ni < 4; ++ni) {
                    int col = bn + wn * 64 + ni * 16 + l15;
                    float v = acc[mi][ni][r] + bval[ni];
                    if (RELU) v = v > 0.f ? v : 0.f;
                    if constexpr (sizeof(OT) == 2)
                        C[(size_t)row * N + col] = f2bf(v);
                    else
                        C[(size_t)row * N + col] = v;
                }
            }
        }
    }
}

extern "C" void kernel_launch(void* const* d_in, const int* in_sizes, int n_in,
                              void* d_out, int out_size, void* d_ws, size_t ws_size,
                              hipStream_t stream) {
    const float* x   = (const float*)d_in[0];
    const int*   ei  = (const int*)d_in[1];
    const float* W1a = (const float*)d_in[2];
    const float* b1a = (const float*)d_in[3];
    const float* W2a = (const float*)d_in[4];
    const float* b2a = (const float*)d_in[5];
    const float* W1b = (const float*)d_in[6];
    const float* b1b = (const float*)d_in[7];
    const float* W2b = (const float*)d_in[8];
    const float* b2b = (const float*)d_in[9];
    const int* src = ei;
    const int* dst = ei + N_EDGES;
    float* out = (float*)d_out;

    // ---- workspace layout (~85MB; 103MB proven to fit) ----
    char* base = (char*)d_ws;
    size_t o = 0;
    ushort_t* wt1a = (ushort_t*)(base + o); o += 128 * 256 * 2;
    ushort_t* wt2a = (ushort_t*)(base + o); o += 256 * 256 * 2;
    ushort_t* wt1b = (ushort_t*)(base + o); o += 256 * 256 * 2;
    ushort_t* wt2b = (ushort_t*)(base + o); o += 256 * 128 * 2;
    o = (o + 255) & ~(size_t)255;
    ushort_t* zrow = (ushort_t*)(base + o); o += 512;          // zeroed dummy row
    int* deg     = (int*)(base + o); o += (size_t)N_NODES * 4; // memset with zrow
    int* row_ptr = (int*)(base + o); o += (size_t)N_NODES * 4;
    int* cursor  = (int*)(base + o); o += (size_t)N_NODES * 4;
    int* bsum    = (int*)(base + o); o += 128 * 4;
    int* boff    = (int*)(base + o); o += 128 * 4;
    o = (o + 255) & ~(size_t)255;
    int* csr_src = (int*)(base + o); o += (size_t)N_EDGES * 4;
    o = (o + 255) & ~(size_t)255;
    ushort_t* t1   = (ushort_t*)(base + o); o += (size_t)N_NODES * 128 * 2;
    ushort_t* tbig = (ushort_t*)(base + o); o += (size_t)N_NODES * 256 * 2;  // u1, then t2
    o += 128 * 1024;  // guard: GEMM A-tail DMA guard is gr<M; this is belt+braces
    (void)ws_size; (void)o; (void)in_sizes; (void)n_in; (void)out_size;

    ushort_t* inter = (ushort_t*)d_out;  // xb, then h, then u2 (d_out = 51.2MB)
    ushort_t* xb    = (ushort_t*)d_out;  // bf16 x, dead after agg1 (GEMM2 overwrites)

    // ---- weights -> bf16 transposed; x -> bf16 ----
    cvt_all_kernel<<<768, 256, 0, stream>>>(W1a, W2a, W1b, W2b,
                                            wt1a, wt2a, wt1b, wt2b);
    cvt_x_kernel<<<(N_NODES * 128 / 8 + 255) / 256, 256, 0, stream>>>(
        x, xb, N_NODES * 128 / 8);

    // ---- CSR build (bucketed hist/fill; reused by both layers) ----
    const int NB = (N_NODES + 1023) / 1024;  // 98
    hipMemsetAsync(zrow, 0, 512 + (size_t)N_NODES * 4, stream);  // zrow + deg
    hist_kernel<<<dim3(1024, NBUCK), 256, 0, stream>>>(src, dst, deg, N_EDGES);
    scan1_kernel<<<NB, 256, 0, stream>>>(deg, bsum, N_NODES);
    scan2_kernel<<<1, 128, 0, stream>>>(bsum, boff, NB);
    scan3_kernel<<<NB, 256, 0, stream>>>(deg, boff, row_ptr, cursor, N_NODES);
    fill_kernel<<<dim3(1024, NBUCK), 256, 0, stream>>>(src, dst, cursor, csr_src,
                                                       N_EDGES);

    const int gm = (N_NODES + 127) / 128;    // 782
    const int ga = (N_NODES + 3) / 4;        // 25000

    // ---- layer 1 ----
    // t1 = xb + segsum(xb)        (d_out -> ws)
    agg_gather_kernel<128, 4><<<ga, 256, 0, stream>>>(xb, t1, row_ptr, deg,
                                                      csr_src, zrow, N_NODES);
    // u1 = relu(t1 @ W1a + b1a)   (ws -> ws)
    gemm_kernel<true, ushort_t><<<dim3(gm, 2), 256, 0, stream>>>(
        t1, wt1a, b1a, tbig, N_NODES, 256, 128);
    // h = relu(u1 @ W2a + b2a)    (ws -> d_out, overwrites dead xb)
    gemm_kernel<true, ushort_t><<<dim3(gm, 2), 256, 0, stream>>>(
        tbig, wt2a, b2a, inter, N_NODES, 256, 256);

    // ---- layer 2 ----
    // t2 = h + segsum(h)          (d_out -> ws, overwrites dead u1)
    agg_gather_kernel<256, 8><<<ga, 256, 0, stream>>>(inter, tbig, row_ptr,
                                                      deg, csr_src, zrow, N_NODES);
    // u2 = relu(t2 @ W1b + b1b)   (ws -> d_out, overwrites dead h)
    gemm_kernel<true, ushort_t><<<dim3(gm, 2), 256, 0, stream>>>(
        tbig, wt1b, b1b, inter, N_NODES, 256, 256);
    // out = u2 @ W2b + b2b        (in-place in d_out, gy=1, equal 512B row extents)
    gemm_kernel<false, float><<<dim3(gm, 1), 256, 0, stream>>>(
        inter, wt2b, b2b, out, N_NODES, 128, 256);
}